// Round 1
// baseline (215.619 us; speedup 1.0000x reference)
//
#include <hip/hip_runtime.h>
#include <math.h>

// LRML distance-embedding head:
//   ue = renorm(user_emb[uid]); ie = renorm(item_emb[iid])       (max_norm=1)
//   scores = softmax((ue*ie) @ W_att^T)   [M=10]
//   rel    = scores @ memory              [D=32]
//   out    = -||ue + rel - ie||^2
//
// Layout: 8 lanes per batch element (D=32 = 8 x float4). Cross-lane reduces
// via __shfl_xor over the aligned 8-lane group. W_att/memory in LDS
// (broadcast reads). One launch, everything else in registers.

#define D 32
#define M 10
#define BLOCK 256
#define LANES_PER_ELEM 8

__global__ __launch_bounds__(BLOCK) void lrml_kernel(
    const int* __restrict__ user_ids,
    const int* __restrict__ item_ids,
    const float* __restrict__ user_emb,
    const float* __restrict__ item_emb,
    const float* __restrict__ W_att,
    const float* __restrict__ memory,
    float* __restrict__ out,
    int B)
{
    // float4-aligned LDS staging for the tiny weight matrices (2 x 320 floats)
    __shared__ float4 s_w4[M * D / 4];    // W_att
    __shared__ float4 s_m4[M * D / 4];    // memory

    {
        float* sw = (float*)s_w4;
        float* sm = (float*)s_m4;
        for (int i = threadIdx.x; i < M * D; i += BLOCK) {
            sw[i] = W_att[i];
            sm[i] = memory[i];
        }
    }
    __syncthreads();

    int gthread = blockIdx.x * BLOCK + threadIdx.x;
    int elem = gthread >> 3;            // batch element
    int g    = gthread & 7;             // quarter-row index within element
    if (elem >= B) return;

    int uid = user_ids[elem];           // 8-way broadcast load
    int iid = item_ids[elem];

    const float4* up = (const float4*)(user_emb + (size_t)uid * D);
    const float4* ip = (const float4*)(item_emb + (size_t)iid * D);
    float4 ue = up[g];                  // coalesced: 8 lanes cover the 128-B row
    float4 ie = ip[g];

    // --- renorm to max L2 norm 1 ---
    float un2 = ue.x*ue.x + ue.y*ue.y + ue.z*ue.z + ue.w*ue.w;
    float in2 = ie.x*ie.x + ie.y*ie.y + ie.z*ie.z + ie.w*ie.w;
    #pragma unroll
    for (int mask = 1; mask < LANES_PER_ELEM; mask <<= 1) {
        un2 += __shfl_xor(un2, mask, 64);
        in2 += __shfl_xor(in2, mask, 64);
    }
    float su = 1.0f / fmaxf(sqrtf(un2), 1.0f);
    float si = 1.0f / fmaxf(sqrtf(in2), 1.0f);
    ue.x *= su; ue.y *= su; ue.z *= su; ue.w *= su;
    ie.x *= si; ie.y *= si; ie.z *= si; ie.w *= si;

    float4 joint;
    joint.x = ue.x * ie.x;
    joint.y = ue.y * ie.y;
    joint.z = ue.z * ie.z;
    joint.w = ue.w * ie.w;

    // --- attention scores: (joint @ W_att^T), partial per lane then reduce ---
    float s[M];
    #pragma unroll
    for (int m = 0; m < M; m++) {
        float4 w = s_w4[m * (D / 4) + g];   // same addr across 8-lane group: broadcast
        s[m] = joint.x*w.x + joint.y*w.y + joint.z*w.z + joint.w*w.w;
    }
    #pragma unroll
    for (int mask = 1; mask < LANES_PER_ELEM; mask <<= 1) {
        #pragma unroll
        for (int m = 0; m < M; m++)
            s[m] += __shfl_xor(s[m], mask, 64);
    }

    // --- softmax over M=10 (redundant per lane, all in registers) ---
    float mx = s[0];
    #pragma unroll
    for (int m = 1; m < M; m++) mx = fmaxf(mx, s[m]);
    float sum = 0.0f;
    #pragma unroll
    for (int m = 0; m < M; m++) {
        s[m] = __expf(s[m] - mx);
        sum += s[m];
    }
    float inv = 1.0f / sum;

    // --- rel = scores @ memory (this lane's quarter of D) ---
    float4 rel = {0.0f, 0.0f, 0.0f, 0.0f};
    #pragma unroll
    for (int m = 0; m < M; m++) {
        float sc = s[m] * inv;
        float4 mm = s_m4[m * (D / 4) + g];
        rel.x += sc * mm.x;
        rel.y += sc * mm.y;
        rel.z += sc * mm.z;
        rel.w += sc * mm.w;
    }

    // --- dist = ||ue + rel - ie||^2, reduce across the 8-lane group ---
    float dx = ue.x + rel.x - ie.x;
    float dy = ue.y + rel.y - ie.y;
    float dz = ue.z + rel.z - ie.z;
    float dw = ue.w + rel.w - ie.w;
    float dist = dx*dx + dy*dy + dz*dz + dw*dw;
    #pragma unroll
    for (int mask = 1; mask < LANES_PER_ELEM; mask <<= 1)
        dist += __shfl_xor(dist, mask, 64);

    if (g == 0) out[elem] = -dist;
}

extern "C" void kernel_launch(void* const* d_in, const int* in_sizes, int n_in,
                              void* d_out, int out_size, void* d_ws, size_t ws_size,
                              hipStream_t stream) {
    const int*   user_ids = (const int*)d_in[0];
    const int*   item_ids = (const int*)d_in[1];
    const float* user_emb = (const float*)d_in[2];
    const float* item_emb = (const float*)d_in[3];
    const float* W_att    = (const float*)d_in[4];
    const float* memory   = (const float*)d_in[5];
    float* out = (float*)d_out;

    int B = in_sizes[0];
    int threads = B * LANES_PER_ELEM;
    int grid = (threads + BLOCK - 1) / BLOCK;

    lrml_kernel<<<grid, BLOCK, 0, stream>>>(
        user_ids, item_ids, user_emb, item_emb, W_att, memory, out, B);
}